// Round 2
// baseline (420.863 us; speedup 1.0000x reference)
//
#include <hip/hip_runtime.h>

typedef _Float16 f16x8 __attribute__((ext_vector_type(8)));
typedef _Float16 f16x4 __attribute__((ext_vector_type(4)));
typedef _Float16 f16x2 __attribute__((ext_vector_type(2)));
typedef float f32x4 __attribute__((ext_vector_type(4)));
typedef float f32x2 __attribute__((ext_vector_type(2)));

#define GLD_LDS16(gp, lp)                                                        \
  __builtin_amdgcn_global_load_lds(                                              \
      (const __attribute__((address_space(1))) void*)(gp),                       \
      (__attribute__((address_space(3))) void*)(lp), 16, 0, 0)

// ---------------- kernel 0: weights -> f16 (Cw = A - B, Bw = B) ----------------
__global__ void prep_weights_k(const float* __restrict__ A, const float* __restrict__ B,
                               _Float16* __restrict__ Cw, _Float16* __restrict__ Bw) {
  int gid = blockIdx.x * 256 + threadIdx.x;
  f32x4 a = ((const f32x4*)A)[gid];
  f32x4 b = ((const f32x4*)B)[gid];
  f16x4 c, bb;
  c.x = (_Float16)(a.x - b.x); c.y = (_Float16)(a.y - b.y);
  c.z = (_Float16)(a.z - b.z); c.w = (_Float16)(a.w - b.w);
  bb.x = (_Float16)b.x; bb.y = (_Float16)b.y;
  bb.z = (_Float16)b.z; bb.w = (_Float16)b.w;
  ((f16x4*)Cw)[gid] = c;
  ((f16x4*)Bw)[gid] = bb;
}

// ---------------- kernel 1: x -> f16, S[b,h] = sum_i x[b,i,h] ----------------
__global__ void prep_x_k(const float* __restrict__ x, _Float16* __restrict__ xh,
                         _Float16* __restrict__ Sh) {
  int b = blockIdx.x, t = threadIdx.x;
  const f32x2* xr = (const f32x2*)(x + (size_t)b * 4096);
  f16x2* xo = (f16x2*)xh + (size_t)b * 2048;
  float s0 = 0.f, s1 = 0.f;
#pragma unroll
  for (int i = 0; i < 8; ++i) {
    f32x2 v = xr[i * 256 + t];
    f16x2 h;
    h.x = (_Float16)v.x; h.y = (_Float16)v.y;
    xo[i * 256 + t] = h;
    s0 += v.x; s1 += v.y;
  }
  f16x2 sv;
  sv.x = (_Float16)s0; sv.y = (_Float16)s1;
  ((f16x2*)Sh)[(size_t)b * 256 + t] = sv;
}

// ---------------- fused GEMM ----------------
// out[m=(b,i), col=(g,h)] = sum_k xh[m,k]*Cw[col,k] + t[b,col],
// t[b,col] = sum_k Sh[b,k]*Bw[col,k] computed in-block (each (b,col) chunk is
// owned by exactly one block: rows of b live in one m-tile, col in one n-tile).
// 128x128 tile, BK=32, 4 waves (2x2 of 64x64), mfma_f32_16x16x32_f16.
// LDS tiles [row][k], 16B chunks XOR-swizzled: phys = logical ^ ((row>>1)&3).
__global__ __launch_bounds__(256) void gemm_fused_k(const _Float16* __restrict__ Am,
                                                    const _Float16* __restrict__ Cw,
                                                    const _Float16* __restrict__ Bw,
                                                    const _Float16* __restrict__ Sh,
                                                    float* __restrict__ out) {
  __shared__ __align__(16) _Float16 lA[128 * 32];
  __shared__ __align__(16) _Float16 lW[128 * 32];
  __shared__ __align__(16) _Float16 lV[128 * 32];  // Bw tile
  __shared__ __align__(16) _Float16 lS[16 * 32];   // S rows for this m-tile

  const int tid = threadIdx.x;
  const int lane = tid & 63;
  const int wv = tid >> 6;
  const int tile_n = blockIdx.x & 15;
  const int tile_m = blockIdx.x >> 4;

  // Staging: tile = 128 rows x 64B = 512 16B-chunks; chunk c = i*256 + tid.
  // global_load_lds writes LDS at (wave-uniform base) + lane*16; swizzle the
  // *global* source k-chunk instead (lc), keeping LDS destination linear.
  const _Float16* gA[2];
  const _Float16* gW[2];
  const _Float16* gV[2];
  _Float16* lpA[2];
  _Float16* lpW[2];
  _Float16* lpV[2];
#pragma unroll
  for (int i = 0; i < 2; ++i) {
    int c = i * 256 + tid;
    int row = c >> 2;
    int lc = (c & 3) ^ ((row >> 1) & 3);
    gA[i] = Am + ((size_t)(tile_m * 128 + row) * 512 + lc * 8);
    gW[i] = Cw + ((size_t)(tile_n * 128 + row) * 512 + lc * 8);
    gV[i] = Bw + ((size_t)(tile_n * 128 + row) * 512 + lc * 8);
    lpA[i] = &lA[(i * 256 + wv * 64) * 8];
    lpW[i] = &lW[(i * 256 + wv * 64) * 8];
    lpV[i] = &lV[(i * 256 + wv * 64) * 8];
  }
  // S staging (wave 0 only): 16 rows x 32 k = 64 chunks; lane -> chunk identity,
  // LDS linear (no swizzle). Per-lane global source is allowed.
  const _Float16* gS =
      Sh + ((size_t)(tile_m * 16 + (lane >> 2)) * 512 + (lane & 3) * 8);

  const int lm = lane & 15;
  const int q = lane >> 4;
  const int mw = (wv >> 1) * 64;  // wave row origin in tile
  const int nw = (wv & 1) * 64;   // wave col origin in tile

  int aoff[4], boff[4], voff[2];
#pragma unroll
  for (int f = 0; f < 4; ++f) {
    int rA = mw + f * 16 + lm;
    aoff[f] = rA * 32 + (q ^ ((rA >> 1) & 3)) * 8;
    int rB = nw + f * 16 + lm;
    boff[f] = rB * 32 + (q ^ ((rB >> 1) & 3)) * 8;
  }
  // t col-fragments: wave wv owns block-cols [wv*32, wv*32+32) (frags 2wv, 2wv+1)
#pragma unroll
  for (int f = 0; f < 2; ++f) {
    int rV = wv * 32 + f * 16 + lm;
    voff[f] = rV * 32 + (q ^ ((rV >> 1) & 3)) * 8;
  }
  const int soff = lm * 32 + q * 8;  // S frag: lane holds S[b=lm][k=q*8+j]

  f32x4 acc[4][4];
  f32x4 tacc[2];
#pragma unroll
  for (int im = 0; im < 4; ++im)
#pragma unroll
    for (int in = 0; in < 4; ++in) acc[im][in] = (f32x4){0.f, 0.f, 0.f, 0.f};
#pragma unroll
  for (int f = 0; f < 2; ++f) tacc[f] = (f32x4){0.f, 0.f, 0.f, 0.f};

  for (int kt = 0; kt < 16; ++kt) {
    __syncthreads();  // prior ds_reads drained before overwrite
#pragma unroll
    for (int i = 0; i < 2; ++i) {
      GLD_LDS16(gA[i] + kt * 32, lpA[i]);
      GLD_LDS16(gW[i] + kt * 32, lpW[i]);
      GLD_LDS16(gV[i] + kt * 32, lpV[i]);
    }
    if (wv == 0) GLD_LDS16(gS + kt * 32, &lS[0]);
    __syncthreads();  // staged data visible (vmcnt drained per-wave pre-barrier)
    f16x8 af[4], bf[4], vf[2], sf;
    sf = *(const f16x8*)&lS[soff];
#pragma unroll
    for (int f = 0; f < 4; ++f) {
      af[f] = *(const f16x8*)&lA[aoff[f]];
      bf[f] = *(const f16x8*)&lW[boff[f]];
    }
#pragma unroll
    for (int f = 0; f < 2; ++f) vf[f] = *(const f16x8*)&lV[voff[f]];
#pragma unroll
    for (int im = 0; im < 4; ++im)
#pragma unroll
      for (int in = 0; in < 4; ++in)
        acc[im][in] =
            __builtin_amdgcn_mfma_f32_16x16x32_f16(af[im], bf[in], acc[im][in], 0, 0, 0);
#pragma unroll
    for (int f = 0; f < 2; ++f)
      tacc[f] = __builtin_amdgcn_mfma_f32_16x16x32_f16(sf, vf[f], tacc[f], 0, 0, 0);
  }

  // Exchange t across waves via LDS (alias onto lA: 16*128 f32 = 8 KB = lA size).
  __syncthreads();  // all lA reads of last K-step done before overwrite
  float* lT = (float*)lA;
#pragma unroll
  for (int f = 0; f < 2; ++f) {
    int colb = wv * 32 + f * 16 + lm;  // tacc C/D: row b = q*4+r, col = colb
#pragma unroll
    for (int r = 0; r < 4; ++r) lT[(q * 4 + r) * 128 + colb] = tacc[f][r];
  }
  __syncthreads();

  // Epilogue. C/D layout: col = lane&15, row = q*4 + reg (m89-verified).
  // mloc..mloc+3 all in the same b (q*4+r spans <8).
#pragma unroll
  for (int im = 0; im < 4; ++im) {
    const int mloc = mw + im * 16 + q * 4;
    const int mbase = tile_m * 128 + mloc;
    const int b = mbase >> 3;
    const int bl = mloc >> 3;  // local b index 0..15
#pragma unroll
    for (int in = 0; in < 4; ++in) {
      const int cl = nw + in * 16 + lm;       // tile-local col
      const int col = tile_n * 128 + cl;      // global col = g*512+h
      const float tv = lT[bl * 128 + cl];
      f32x4 v = acc[im][in];
      float* op = out + (size_t)b * 16384 + (size_t)(col >> 9) * 4096 +
                  (size_t)(mbase & 7) * 512 + (col & 511);
#pragma unroll
      for (int r = 0; r < 4; ++r) op[r * 512] = v[r] + tv;
    }
  }
}

extern "C" void kernel_launch(void* const* d_in, const int* in_sizes, int n_in,
                              void* d_out, int out_size, void* d_ws, size_t ws_size,
                              hipStream_t stream) {
  const float* x = (const float*)d_in[0];  // [4096, 4096]
  const float* A = (const float*)d_in[1];  // [4, 512, 512]
  const float* B = (const float*)d_in[2];  // [4, 512, 512]
  float* out = (float*)d_out;              // [4096, 16384]
  char* ws = (char*)d_ws;

  // ws layout (bytes): xh f16[32768*512] @0 (32MB); Sh f16[4096*512] @32MB (4MB);
  // Cw f16[2048*512] @36MB (2MB); Bw f16[2048*512] @38MB (2MB)
  _Float16* xh = (_Float16*)(ws);
  _Float16* Sh = (_Float16*)(ws + 33554432u);
  _Float16* Cw = (_Float16*)(ws + 37748736u);
  _Float16* Bw = (_Float16*)(ws + 39845888u);

  prep_weights_k<<<1024, 256, 0, stream>>>(A, B, Cw, Bw);
  prep_x_k<<<4096, 256, 0, stream>>>(x, xh, Sh);
  // out = xh @ Cw^T + t, t fused: M=32768 -> 256 m-tiles, 16 n-tiles
  gemm_fused_k<<<4096, 256, 0, stream>>>(xh, Cw, Bw, Sh, out);
}